// Round 8
// baseline (3525.582 us; speedup 1.0000x reference)
//
#include <hip/hip_runtime.h>
#include <hip/hip_bf16.h>
#include <math.h>

#define D_IN 56
#define H    501
#define T_STEPS 277
#define O_OUT 76
#define BATCH 256
#define HP   512    // padded K (hidden) for MFMA
#define NP   1504   // padded 3H
#define SSTR 520    // LDS staging row stride in shorts (1040B, 16B-aligned)

// dynamic LDS layout: SA | SB | SC | hgl[18][544] | sg0[32*48] | sb[3*4*16]
#define LDS_SA    0
#define LDS_SB    (32 * SSTR)
#define LDS_SC    (64 * SSTR)
#define LDS_STAGE (96 * SSTR)                 // 99,840 B staging (shorts)
#define DYN_LDS   (96 * SSTR * 2 + 18 * 544 * 4 + 32 * 48 * 4 + 3 * 4 * 16 * 4)  // 145,920

typedef __attribute__((ext_vector_type(8))) short s16x8;
typedef __attribute__((ext_vector_type(4))) float f32x4;
typedef unsigned long long ull;

__device__ __forceinline__ short f2bf(float x) {
    union { float f; unsigned u; } v; v.f = x;
    unsigned r = (v.u + 0x7fffu + ((v.u >> 16) & 1u)) >> 16;
    return (short)r;
}
__device__ __forceinline__ float bf2f(short b) {
    union { unsigned u; float f; } v; v.u = ((unsigned)(unsigned short)b) << 16;
    return v.f;
}
__device__ __forceinline__ float sigm(float x) { return 1.f / (1.f + __expf(-x)); }
__device__ __forceinline__ float tanh_fast(float x) { return 1.f - 2.f / (1.f + __expf(2.f * x)); }

// ---------------------------------------------------------------------------
// Weight packing (unchanged, proven correct)
// ---------------------------------------------------------------------------
__global__ void k_pack_gru(const float* __restrict__ w_ih,
                           const float* __restrict__ w_hh,
                           short* __restrict__ dst, int KT) {
    int tile = blockIdx.x;
    int ktp  = tile % KT;
    int g    = (tile / KT) % 3;
    int j    = tile / (KT * 3);
    int l    = threadIdx.x;
    int u    = j * 16 + (l & 15);
    int row  = g * H + u;
    const float* src; int k0;
    if (KT == 32) {
        if (ktp < 16) { src = w_ih; k0 = ktp * 32; }
        else          { src = w_hh; k0 = (ktp - 16) * 32; }
    } else          { src = w_hh; k0 = ktp * 32; }
    k0 += (l >> 4) * 8;
    short* p = dst + ((size_t)tile * 64 + l) * 8;
    for (int jj = 0; jj < 8; jj++) {
        int k = k0 + jj;
        float v = 0.f;
        if (u < H && k < H) v = src[(size_t)row * H + k];
        p[jj] = f2bf(v);
    }
}

__global__ void k_pack_fc2(const float* __restrict__ w, short* __restrict__ dst) {
    int tile = blockIdx.x;
    int kt = tile % 16, mt = tile / 16;
    int l = threadIdx.x;
    int o = mt * 16 + (l & 15);
    int k0 = kt * 32 + (l >> 4) * 8;
    short* p = dst + ((size_t)tile * 64 + l) * 8;
    for (int jj = 0; jj < 8; jj++) {
        int k = k0 + jj; float v = 0.f;
        if (o < O_OUT && k < H) v = w[(size_t)o * H + k];
        p[jj] = f2bf(v);
    }
}

__global__ void k_hin(const float* __restrict__ x, const float* __restrict__ w,
                      const float* __restrict__ bias, float* __restrict__ hin) {
    int b = blockIdx.x, o = threadIdx.x;
    float acc = 0.f;
    if (o < D_IN) {
        acc = bias[o];
        for (int k = 0; k < D_IN; k++) acc += x[b * D_IN + k] * w[o * D_IN + k];
        acc = fmaxf(acc, 0.f);
    }
    hin[b * 64 + o] = (o < D_IN) ? acc : 0.f;
}

__global__ void k_g0(const float* __restrict__ hin, const float* __restrict__ w_ih0,
                     const float* __restrict__ b_ih0, float* __restrict__ g0) {
    int b = blockIdx.x, tid = threadIdx.x;
    __shared__ float shx[D_IN];
    if (tid < D_IN) shx[tid] = hin[b * 64 + tid];
    __syncthreads();
    for (int o = tid; o < NP; o += 256) {
        float acc = 0.f;
        if (o < 3 * H) {
            acc = b_ih0[o];
            for (int k = 0; k < D_IN; k++) acc += shx[k] * w_ih0[(size_t)o * D_IN + k];
        }
        g0[(size_t)b * NP + o] = acc;
    }
}

// ---------------------------------------------------------------------------
// Persistent pipelined GRU — R8: waves own (layer, K-range) and compute ALL
// 3 gates per A-read (one ds_read_b128 feeds 3 MFMAs). LDS reads/block drop
// 480 -> 160 vs R7. hgl slot layout identical to R7 (part = K-range), so the
// gate phase is unchanged; ih/hh K-split preserves the xn/hn separation.
//   w0: l0 hh k[0:256)   A=SA -> part0      w1: l0 hh k[256:512) A=SA -> part1
//   w2: l1 ih            A=SA -> part0      w3: l1 hh            A=SB -> part1
//   w4: l2 ih            A=SB -> part0      w5: l2 hh            A=SC -> part1
// Inactive epochs are staged as zeros, so zero-A MFMAs reproduce guards.
// ---------------------------------------------------------------------------
__global__ __launch_bounds__(384, 1)
void k_gru_persist(const short* __restrict__ packW0,
                   const short* __restrict__ packW1,
                   const short* __restrict__ packW2,
                   const float* __restrict__ g0,
                   const float* __restrict__ b_hh0,
                   const float* __restrict__ b_ih1, const float* __restrict__ b_hh1,
                   const float* __restrict__ b_ih2, const float* __restrict__ b_hh2,
                   short* __restrict__ ysA,    // layer0 out at t, overwritten by layer2 at t (step t+2)
                   short* __restrict__ ysB,    // layer1 out
                   unsigned* __restrict__ cnt) {
    const int bg   = blockIdx.x >> 5;                          // batch group 0..7
    const int j    = ((blockIdx.x & 7) << 2) | ((blockIdx.x >> 3) & 3); // XCD-local slice
    const int b0   = bg * 32;
    const int tid  = threadIdx.x;
    const int lane = tid & 63;
    const int wave = tid >> 6;
    const int arow = lane & 15;
    const int acol = (lane >> 4) * 8;
    const s16x8 z8 = {0, 0, 0, 0, 0, 0, 0, 0};

    extern __shared__ __align__(16) char smem[];
    short* stg = (short*)smem;                         // SA/SB/SC
    float* hgl = (float*)(smem + LDS_STAGE * 2);       // [18][544]
    float* sg0 = hgl + 18 * 544;                       // [32*48]
    float* sbb = sg0 + 32 * 48;                        // [3][4][16]

    // ---- wave role: layer, ktp range, A-tile base, weight pack, hgl part
    int layer, kt0, nk, abase, part; const short* wpk; int KT;
    switch (wave) {
        case 0:  layer = 0; kt0 = 0;  nk = 8;  abase = LDS_SA; wpk = packW0; KT = 16; part = 0; break;
        case 1:  layer = 0; kt0 = 8;  nk = 8;  abase = LDS_SA; wpk = packW0; KT = 16; part = 1; break;
        case 2:  layer = 1; kt0 = 0;  nk = 16; abase = LDS_SA; wpk = packW1; KT = 32; part = 0; break;
        case 3:  layer = 1; kt0 = 16; nk = 16; abase = LDS_SB; wpk = packW1; KT = 32; part = 1; break;
        case 4:  layer = 2; kt0 = 0;  nk = 16; abase = LDS_SB; wpk = packW2; KT = 32; part = 0; break;
        default: layer = 2; kt0 = 16; nk = 16; abase = LDS_SC; wpk = packW2; KT = 32; part = 1; break;
    }
    // A-tile k index: hh waves of KT=32 packs map ktp 16..31 -> tile k 0..15
    const int aoff = (KT == 32 && part == 1) ? -16 : 0;
    // weight tile pointers for the 3 gates (1 KB per tile, 512 shorts)
    const short* wg0 = wpk + ((size_t)((j * 3 + 0) * KT + kt0) * 512);
    const short* wg1 = wpk + ((size_t)((j * 3 + 1) * KT + kt0) * 512);
    const short* wg2 = wpk + ((size_t)((j * 3 + 2) * KT + kt0) * 512);

    // ---- layer0 x-gate constants (g0 + b_hh0 folded for r,z)
    for (int c = tid; c < 32 * 48; c += 384) {
        int m = c / 48, col = c % 48;
        int g = col >> 4, ul = col & 15;
        int u = j * 16 + ul;
        float v = 0.f;
        if (u < H) {
            v = g0[(size_t)(b0 + m) * NP + g * H + u];
            if (g == 0) v += b_hh0[u];
            else if (g == 1) v += b_hh0[H + u];
        }
        sg0[m * 48 + col] = v;
    }
    if (tid < 48) {
        int l = tid >> 4, ul = tid & 15, u = j * 16 + ul;
        float br = 0.f, bz = 0.f, bxn = 0.f, bhn = 0.f;
        if (u < H) {
            if (l == 0) bhn = b_hh0[2 * H + u];
            else {
                const float* bi = (l == 1) ? b_ih1 : b_ih2;
                const float* bh = (l == 1) ? b_hh1 : b_hh2;
                br = bi[u] + bh[u]; bz = bi[H + u] + bh[H + u];
                bxn = bi[2 * H + u]; bhn = bh[2 * H + u];
            }
        }
        sbb[(l * 4 + 0) * 16 + ul] = br;  sbb[(l * 4 + 1) * 16 + ul] = bz;
        sbb[(l * 4 + 2) * 16 + ul] = bxn; sbb[(l * 4 + 3) * 16 + ul] = bhn;
    }
    __syncthreads();

    unsigned* mycnt = cnt + bg * 32;   // 128B-strided counters

    for (int s = 0; s < T_STEPS + 2; ++s) {
        const bool hasL0 = (s < T_STEPS);
        const bool hasL1 = (s >= 1 && s <= T_STEPS);
        const bool hasL2 = (s >= 2);
        const short* ysAm1 = ysA + (size_t)(s - 1) * BATCH * HP;
        const short* ysBm2 = ysB + (size_t)(s - 2) * BATCH * HP;
        const short* ysAm3 = ysA + (size_t)(s - 3) * BATCH * HP;

        // ================= PHASE A: coalesced staging of all three tiles ====
        #pragma unroll
        for (int i = 0; i < 6; i++) {
            int c = tid + i * 384;
            if (c < 2048) {
                int r = c >> 6, cc = c & 63;
                size_t goff = (size_t)(b0 + r) * HP + cc * 8;
                s16x8 va = z8, vb = z8, vc = z8;
                if (s >= 1 && s <= T_STEPS) va = *(const s16x8*)&ysAm1[goff];
                if (s >= 2)                 vb = *(const s16x8*)&ysBm2[goff];
                if (s >= 3) {
                    const ull* p = (const ull*)&ysAm3[goff];
                    union { ull q[2]; s16x8 v; } uu;
                    uu.q[0] = __hip_atomic_load(p,     __ATOMIC_RELAXED, __HIP_MEMORY_SCOPE_AGENT);
                    uu.q[1] = __hip_atomic_load(p + 1, __ATOMIC_RELAXED, __HIP_MEMORY_SCOPE_AGENT);
                    vc = uu.v;
                }
                int loff = r * SSTR + cc * 8;
                *(s16x8*)&stg[LDS_SA + loff] = va;
                *(s16x8*)&stg[LDS_SB + loff] = vb;
                *(s16x8*)&stg[LDS_SC + loff] = vc;
            }
        }
        __syncthreads();                                   // (1) tiles staged

        // ================= PHASE B: all MFMAs (3 gates per A-read) ==========
        {
            const bool active = (layer == 0) ? hasL0 : ((layer == 1) ? hasL1 : hasL2);
            f32x4 ar0 = {0.f,0.f,0.f,0.f}, ar1 = {0.f,0.f,0.f,0.f};
            f32x4 az0 = {0.f,0.f,0.f,0.f}, az1 = {0.f,0.f,0.f,0.f};
            f32x4 an0 = {0.f,0.f,0.f,0.f}, an1 = {0.f,0.f,0.f,0.f};
            if (active) {
                #pragma unroll 4
                for (int kk = 0; kk < nk; kk++) {
                    int ak = kt0 + kk + aoff;              // A-tile k index
                    s16x8 x0 = *(const s16x8*)&stg[abase + arow * SSTR + ak * 32 + acol];
                    s16x8 x1 = *(const s16x8*)&stg[abase + (16 + arow) * SSTR + ak * 32 + acol];
                    s16x8 br = *(const s16x8*)&wg0[(size_t)kk * 512 + lane * 8];
                    s16x8 bz = *(const s16x8*)&wg1[(size_t)kk * 512 + lane * 8];
                    s16x8 bn = *(const s16x8*)&wg2[(size_t)kk * 512 + lane * 8];
                    ar0 = __builtin_amdgcn_mfma_f32_16x16x32_bf16(x0, br, ar0, 0, 0, 0);
                    ar1 = __builtin_amdgcn_mfma_f32_16x16x32_bf16(x1, br, ar1, 0, 0, 0);
                    az0 = __builtin_amdgcn_mfma_f32_16x16x32_bf16(x0, bz, az0, 0, 0, 0);
                    az1 = __builtin_amdgcn_mfma_f32_16x16x32_bf16(x1, bz, az1, 0, 0, 0);
                    an0 = __builtin_amdgcn_mfma_f32_16x16x32_bf16(x0, bn, an0, 0, 0, 0);
                    an1 = __builtin_amdgcn_mfma_f32_16x16x32_bf16(x1, bn, an1, 0, 0, 0);
                }
            }
            // write-out: hgl[layer*6 + g*2 + part], C layout m=(lane>>4)*4+r
            int ul = lane & 15, mrow = (lane >> 4) * 4;
            float* dr = hgl + (layer * 6 + 0 * 2 + part) * 544;
            float* dz = hgl + (layer * 6 + 1 * 2 + part) * 544;
            float* dn = hgl + (layer * 6 + 2 * 2 + part) * 544;
            #pragma unroll
            for (int r = 0; r < 4; r++) {
                dr[(mrow + r) * 17 + ul]      = ar0[r];
                dr[(16 + mrow + r) * 17 + ul] = ar1[r];
                dz[(mrow + r) * 17 + ul]      = az0[r];
                dz[(16 + mrow + r) * 17 + ul] = az1[r];
                dn[(mrow + r) * 17 + ul]      = an0[r];
                dn[(16 + mrow + r) * 17 + ul] = an1[r];
            }
        }
        __syncthreads();                                   // (2) hgl complete

        // ================= PHASE C: all gates (768 items / 384 threads) =====
        #pragma unroll
        for (int it = 0; it < 2; it++) {
            int idx = tid + it * 384;
            int which = idx >> 8, id8 = idx & 255;
            int m = id8 >> 3, pr = id8 & 7;
            int b = b0 + m;
            if (which == 0 && hasL0) {
                short* dst = ysA + (size_t)s * BATCH * HP;
                unsigned pk = 0;
                #pragma unroll
                for (int e = 0; e < 2; e++) {
                    int ul = pr * 2 + e, u = j * 16 + ul, mo = m * 17 + ul;
                    float hv = 0.f;
                    if (u < H) {
                        float hr = hgl[0 * 544 + mo] + hgl[1 * 544 + mo];
                        float hz = hgl[2 * 544 + mo] + hgl[3 * 544 + mo];
                        float hn = hgl[4 * 544 + mo] + hgl[5 * 544 + mo];
                        float r = sigm(sg0[m * 48 + ul] + hr);
                        float z = sigm(sg0[m * 48 + 16 + ul] + hz);
                        float n = tanh_fast(sg0[m * 48 + 32 + ul] + r * (hn + sbb[3 * 16 + ul]));
                        float hold = bf2f(stg[LDS_SA + m * SSTR + u]);
                        hv = (1.f - z) * n + z * hold;
                    }
                    pk |= ((unsigned)(unsigned short)f2bf(hv)) << (16 * e);
                }
                __hip_atomic_store((unsigned*)&dst[(size_t)b * HP + j * 16 + pr * 2], pk,
                                   __ATOMIC_RELAXED, __HIP_MEMORY_SCOPE_AGENT);
            } else if (which == 1 && hasL1) {
                short* dst = ysB + (size_t)(s - 1) * BATCH * HP;
                unsigned pk = 0;
                #pragma unroll
                for (int e = 0; e < 2; e++) {
                    int ul = pr * 2 + e, u = j * 16 + ul, mo = m * 17 + ul;
                    float hv = 0.f;
                    if (u < H) {
                        float xr = hgl[6 * 544 + mo]  + sbb[(4 + 0) * 16 + ul];
                        float hr = hgl[7 * 544 + mo];
                        float xz = hgl[8 * 544 + mo]  + sbb[(4 + 1) * 16 + ul];
                        float hz = hgl[9 * 544 + mo];
                        float xn = hgl[10 * 544 + mo] + sbb[(4 + 2) * 16 + ul];
                        float hn = hgl[11 * 544 + mo] + sbb[(4 + 3) * 16 + ul];
                        float r = sigm(xr + hr);
                        float z = sigm(xz + hz);
                        float n = tanh_fast(xn + r * hn);
                        float hold = bf2f(stg[LDS_SB + m * SSTR + u]);
                        hv = (1.f - z) * n + z * hold;
                    }
                    pk |= ((unsigned)(unsigned short)f2bf(hv)) << (16 * e);
                }
                __hip_atomic_store((unsigned*)&dst[(size_t)b * HP + j * 16 + pr * 2], pk,
                                   __ATOMIC_RELAXED, __HIP_MEMORY_SCOPE_AGENT);
            } else if (which == 2 && hasL2) {
                short* dst = ysA + (size_t)(s - 2) * BATCH * HP;
                unsigned pk = 0;
                #pragma unroll
                for (int e = 0; e < 2; e++) {
                    int ul = pr * 2 + e, u = j * 16 + ul, mo = m * 17 + ul;
                    float hv = 0.f;
                    if (u < H) {
                        float xr = hgl[12 * 544 + mo] + sbb[(8 + 0) * 16 + ul];
                        float hr = hgl[13 * 544 + mo];
                        float xz = hgl[14 * 544 + mo] + sbb[(8 + 1) * 16 + ul];
                        float hz = hgl[15 * 544 + mo];
                        float xn = hgl[16 * 544 + mo] + sbb[(8 + 2) * 16 + ul];
                        float hn = hgl[17 * 544 + mo] + sbb[(8 + 3) * 16 + ul];
                        float r = sigm(xr + hr);
                        float z = sigm(xz + hz);
                        float n = tanh_fast(xn + r * hn);
                        float hold = bf2f(stg[LDS_SC + m * SSTR + u]);
                        hv = (1.f - z) * n + z * hold;
                    }
                    pk |= ((unsigned)(unsigned short)f2bf(hv)) << (16 * e);
                }
                __hip_atomic_store((unsigned*)&dst[(size_t)b * HP + j * 16 + pr * 2], pk,
                                   __ATOMIC_RELAXED, __HIP_MEMORY_SCOPE_AGENT);
            }
        }
        __syncthreads();    // (3) every wave's sc1 stores drained at barrier

        // ---- per-bg 32-block barrier: relaxed add + relaxed poll
        if (tid == 0) {
            asm volatile("s_waitcnt vmcnt(0)" ::: "memory");
            __hip_atomic_fetch_add(mycnt, 1u, __ATOMIC_RELAXED, __HIP_MEMORY_SCOPE_AGENT);
            unsigned tgt = 32u * (unsigned)(s + 1);
            while (__hip_atomic_load(mycnt, __ATOMIC_RELAXED, __HIP_MEMORY_SCOPE_AGENT) < tgt) {}
        }
        __syncthreads();                                   // (4)
    }
}

// ---------------------------------------------------------------------------
// fc2 + transpose (reads ysA = layer2 output; fresh kernel => coherent)
// ---------------------------------------------------------------------------
__global__ __launch_bounds__(256, 1)
void k_fc2(const short* __restrict__ ys2, const short* __restrict__ fc2p,
           const float* __restrict__ fc2_b, float* __restrict__ out) {
    int b = blockIdx.x;
    int tid = threadIdx.x, lane = tid & 63, wave = tid >> 6;
    const s16x8 zf = {0, 0, 0, 0, 0, 0, 0, 0};
    for (int ntile = wave; ntile < 18; ntile += 4) {
        int tt = ntile * 16 + (lane & 15);
        s16x8 bf[16];
        for (int kt = 0; kt < 16; kt++) {
            if (tt < T_STEPS)
                bf[kt] = *(const s16x8*)&ys2[((size_t)tt * BATCH + b) * HP + kt * 32 + (lane >> 4) * 8];
            else
                bf[kt] = zf;
        }
        for (int mt = 0; mt < 5; mt++) {
            f32x4 acc = {0.f, 0.f, 0.f, 0.f};
            for (int kt = 0; kt < 16; kt++) {
                s16x8 af = *(const s16x8*)&fc2p[(((size_t)mt * 16 + kt) * 64 + lane) * 8];
                acc = __builtin_amdgcn_mfma_f32_16x16x32_bf16(af, bf[kt], acc, 0, 0, 0);
            }
            int obase = mt * 16 + (lane >> 4) * 4;
            for (int r = 0; r < 4; r++) {
                int o = obase + r;
                if (o < O_OUT && tt < T_STEPS)
                    out[((size_t)b * O_OUT + o) * T_STEPS + tt] = acc[r] + fc2_b[o];
            }
        }
    }
}

// ---------------------------------------------------------------------------
extern "C" void kernel_launch(void* const* d_in, const int* in_sizes, int n_in,
                              void* d_out, int out_size, void* d_ws, size_t ws_size,
                              hipStream_t stream) {
    const float* x     = (const float*)d_in[0];
    const float* fc1_w = (const float*)d_in[1];
    const float* fc1_b = (const float*)d_in[2];
    const float* w_ih0 = (const float*)d_in[3];
    const float* w_hh0 = (const float*)d_in[4];
    const float* b_ih0 = (const float*)d_in[5];
    const float* b_hh0 = (const float*)d_in[6];
    const float* w_ih1 = (const float*)d_in[7];
    const float* w_hh1 = (const float*)d_in[8];
    const float* b_ih1 = (const float*)d_in[9];
    const float* b_hh1 = (const float*)d_in[10];
    const float* w_ih2 = (const float*)d_in[11];
    const float* w_hh2 = (const float*)d_in[12];
    const float* b_ih2 = (const float*)d_in[13];
    const float* b_hh2 = (const float*)d_in[14];
    const float* fc2_w = (const float*)d_in[15];
    const float* fc2_b = (const float*)d_in[16];
    float* out = (float*)d_out;

    char* p = (char*)d_ws;
    auto alloc = [&](size_t bytes) {
        char* r = p; p += (bytes + 255) & ~(size_t)255; return r;
    };
    short* packW0 = (short*)alloc((size_t)32 * 3 * 16 * 64 * 8 * 2);
    short* packW1 = (short*)alloc((size_t)32 * 3 * 32 * 64 * 8 * 2);
    short* packW2 = (short*)alloc((size_t)32 * 3 * 32 * 64 * 8 * 2);
    short* packF  = (short*)alloc((size_t)80 * 64 * 8 * 2);
    float* hin    = (float*)alloc((size_t)BATCH * 64 * 4);
    float* g0     = (float*)alloc((size_t)BATCH * NP * 4);
    unsigned* cnt = (unsigned*)alloc(256 * 4);
    short* ysA    = (short*)alloc((size_t)T_STEPS * BATCH * HP * 2);
    short* ysB    = (short*)alloc((size_t)T_STEPS * BATCH * HP * 2);

    // opt in to >64KB dynamic LDS (host-side attribute; graph-capture safe)
    static bool attr_set = false;
    if (!attr_set) {
        (void)hipFuncSetAttribute((const void*)k_gru_persist,
                                  hipFuncAttributeMaxDynamicSharedMemorySize,
                                  DYN_LDS);
        attr_set = true;
    }

    hipMemsetAsync(cnt, 0, 256 * 4, stream);
    k_pack_gru<<<32 * 3 * 16, 64, 0, stream>>>(nullptr, w_hh0, packW0, 16);
    k_pack_gru<<<32 * 3 * 32, 64, 0, stream>>>(w_ih1, w_hh1, packW1, 32);
    k_pack_gru<<<32 * 3 * 32, 64, 0, stream>>>(w_ih2, w_hh2, packW2, 32);
    k_pack_fc2<<<80, 64, 0, stream>>>(fc2_w, packF);
    k_hin<<<BATCH, 64, 0, stream>>>(x, fc1_w, fc1_b, hin);
    k_g0<<<BATCH, 256, 0, stream>>>(hin, w_ih0, b_ih0, g0);

    k_gru_persist<<<256, 384, DYN_LDS, stream>>>(packW0, packW1, packW2, g0,
                                                 b_hh0, b_ih1, b_hh1, b_ih2, b_hh2,
                                                 ysA, ysB, cnt);

    k_fc2<<<BATCH, 256, 0, stream>>>(ysA, packF, fc2_b, out);
}

// Round 9
// 2410.612 us; speedup vs baseline: 1.4625x; 1.4625x over previous
//
#include <hip/hip_runtime.h>
#include <hip/hip_bf16.h>
#include <math.h>

#define D_IN 56
#define H    501
#define T_STEPS 277
#define O_OUT 76
#define BATCH 256
#define HP   512    // padded K (hidden) for MFMA
#define NP   1504   // padded 3H
#define SSTR 520    // LDS staging row stride in shorts (1040B, 16B-aligned)
#define HSTR 576    // hgl slot size in floats (32 rows * 18)

// dynamic LDS layout: SA | SB | SC | hgl[18][576] | sg0[32*48] | sb[3*4*16]
#define LDS_SA    0
#define LDS_SB    (32 * SSTR)
#define LDS_SC    (64 * SSTR)
#define LDS_STAGE (96 * SSTR)                 // 99,840 B staging (shorts)
#define DYN_LDS   (96 * SSTR * 2 + 18 * HSTR * 4 + 32 * 48 * 4 + 3 * 4 * 16 * 4)  // 148,224

typedef __attribute__((ext_vector_type(8))) short s16x8;
typedef __attribute__((ext_vector_type(4))) float f32x4;
typedef unsigned long long ull;

__device__ __forceinline__ short f2bf(float x) {
    union { float f; unsigned u; } v; v.f = x;
    unsigned r = (v.u + 0x7fffu + ((v.u >> 16) & 1u)) >> 16;
    return (short)r;
}
__device__ __forceinline__ float bf2f(short b) {
    union { unsigned u; float f; } v; v.u = ((unsigned)(unsigned short)b) << 16;
    return v.f;
}
__device__ __forceinline__ float sigm(float x) { return 1.f / (1.f + __expf(-x)); }
__device__ __forceinline__ float tanh_fast(float x) { return 1.f - 2.f / (1.f + __expf(2.f * x)); }

// ---------------------------------------------------------------------------
// Weight packing (unchanged, proven correct)
// ---------------------------------------------------------------------------
__global__ void k_pack_gru(const float* __restrict__ w_ih,
                           const float* __restrict__ w_hh,
                           short* __restrict__ dst, int KT) {
    int tile = blockIdx.x;
    int ktp  = tile % KT;
    int g    = (tile / KT) % 3;
    int j    = tile / (KT * 3);
    int l    = threadIdx.x;
    int u    = j * 16 + (l & 15);
    int row  = g * H + u;
    const float* src; int k0;
    if (KT == 32) {
        if (ktp < 16) { src = w_ih; k0 = ktp * 32; }
        else          { src = w_hh; k0 = (ktp - 16) * 32; }
    } else          { src = w_hh; k0 = ktp * 32; }
    k0 += (l >> 4) * 8;
    short* p = dst + ((size_t)tile * 64 + l) * 8;
    for (int jj = 0; jj < 8; jj++) {
        int k = k0 + jj;
        float v = 0.f;
        if (u < H && k < H) v = src[(size_t)row * H + k];
        p[jj] = f2bf(v);
    }
}

__global__ void k_pack_fc2(const float* __restrict__ w, short* __restrict__ dst) {
    int tile = blockIdx.x;
    int kt = tile % 16, mt = tile / 16;
    int l = threadIdx.x;
    int o = mt * 16 + (l & 15);
    int k0 = kt * 32 + (l >> 4) * 8;
    short* p = dst + ((size_t)tile * 64 + l) * 8;
    for (int jj = 0; jj < 8; jj++) {
        int k = k0 + jj; float v = 0.f;
        if (o < O_OUT && k < H) v = w[(size_t)o * H + k];
        p[jj] = f2bf(v);
    }
}

__global__ void k_hin(const float* __restrict__ x, const float* __restrict__ w,
                      const float* __restrict__ bias, float* __restrict__ hin) {
    int b = blockIdx.x, o = threadIdx.x;
    float acc = 0.f;
    if (o < D_IN) {
        acc = bias[o];
        for (int k = 0; k < D_IN; k++) acc += x[b * D_IN + k] * w[o * D_IN + k];
        acc = fmaxf(acc, 0.f);
    }
    hin[b * 64 + o] = (o < D_IN) ? acc : 0.f;
}

__global__ void k_g0(const float* __restrict__ hin, const float* __restrict__ w_ih0,
                     const float* __restrict__ b_ih0, float* __restrict__ g0) {
    int b = blockIdx.x, tid = threadIdx.x;
    __shared__ float shx[D_IN];
    if (tid < D_IN) shx[tid] = hin[b * 64 + tid];
    __syncthreads();
    for (int o = tid; o < NP; o += 256) {
        float acc = 0.f;
        if (o < 3 * H) {
            acc = b_ih0[o];
            for (int k = 0; k < D_IN; k++) acc += shx[k] * w_ih0[(size_t)o * D_IN + k];
        }
        g0[(size_t)b * NP + o] = acc;
    }
}

// ---------------------------------------------------------------------------
// One wave role of phase B: NK fully unrolled at compile time; one A-read
// (ds_read_b128 pair) feeds 6 MFMAs (3 gates x 2 row-blocks).
// ---------------------------------------------------------------------------
template <int NK>
__device__ __forceinline__ void role_mfma(const short* __restrict__ stg, int abase, int ak0,
                                          const short* __restrict__ wg0,
                                          const short* __restrict__ wg1,
                                          const short* __restrict__ wg2,
                                          float* __restrict__ dr, float* __restrict__ dz,
                                          float* __restrict__ dn, int lane) {
    const int arow = lane & 15;
    const int acol = (lane >> 4) * 8;
    f32x4 ar0 = {0.f,0.f,0.f,0.f}, ar1 = {0.f,0.f,0.f,0.f};
    f32x4 az0 = {0.f,0.f,0.f,0.f}, az1 = {0.f,0.f,0.f,0.f};
    f32x4 an0 = {0.f,0.f,0.f,0.f}, an1 = {0.f,0.f,0.f,0.f};
    #pragma unroll
    for (int kk = 0; kk < NK; kk++) {
        int ak = ak0 + kk;
        s16x8 x0 = *(const s16x8*)&stg[abase + arow * SSTR + ak * 32 + acol];
        s16x8 x1 = *(const s16x8*)&stg[abase + (16 + arow) * SSTR + ak * 32 + acol];
        s16x8 br = *(const s16x8*)&wg0[(size_t)kk * 512 + lane * 8];
        s16x8 bz = *(const s16x8*)&wg1[(size_t)kk * 512 + lane * 8];
        s16x8 bn = *(const s16x8*)&wg2[(size_t)kk * 512 + lane * 8];
        ar0 = __builtin_amdgcn_mfma_f32_16x16x32_bf16(x0, br, ar0, 0, 0, 0);
        ar1 = __builtin_amdgcn_mfma_f32_16x16x32_bf16(x1, br, ar1, 0, 0, 0);
        az0 = __builtin_amdgcn_mfma_f32_16x16x32_bf16(x0, bz, az0, 0, 0, 0);
        az1 = __builtin_amdgcn_mfma_f32_16x16x32_bf16(x1, bz, az1, 0, 0, 0);
        an0 = __builtin_amdgcn_mfma_f32_16x16x32_bf16(x0, bn, an0, 0, 0, 0);
        an1 = __builtin_amdgcn_mfma_f32_16x16x32_bf16(x1, bn, an1, 0, 0, 0);
    }
    int ul = lane & 15, mrow = (lane >> 4) * 4;
    #pragma unroll
    for (int r = 0; r < 4; r++) {
        dr[(mrow + r) * 18 + ul]      = ar0[r];
        dr[(16 + mrow + r) * 18 + ul] = ar1[r];
        dz[(mrow + r) * 18 + ul]      = az0[r];
        dz[(16 + mrow + r) * 18 + ul] = az1[r];
        dn[(mrow + r) * 18 + ul]      = an0[r];
        dn[(16 + mrow + r) * 18 + ul] = an1[r];
    }
}

// ---------------------------------------------------------------------------
// Persistent pipelined GRU — R9: R7 structure + 6 fixed wave roles (3 gates
// per A-read) with compile-time-unrolled loops + hgl stride 18.
//   w0: l0 hh k[0:8)   A=SA part0     w1: l0 hh k[8:16) A=SA part1
//   w2: l1 ih          A=SA part0     w3: l1 hh         A=SB part1
//   w4: l2 ih          A=SB part0     w5: l2 hh         A=SC part1
// ---------------------------------------------------------------------------
__global__ __launch_bounds__(384, 1)
void k_gru_persist(const short* __restrict__ packW0,
                   const short* __restrict__ packW1,
                   const short* __restrict__ packW2,
                   const float* __restrict__ g0,
                   const float* __restrict__ b_hh0,
                   const float* __restrict__ b_ih1, const float* __restrict__ b_hh1,
                   const float* __restrict__ b_ih2, const float* __restrict__ b_hh2,
                   short* __restrict__ ysA,    // layer0 out at t, overwritten by layer2 at t (step t+2)
                   short* __restrict__ ysB,    // layer1 out
                   unsigned* __restrict__ cnt) {
    const int bg   = blockIdx.x >> 5;                          // batch group 0..7
    const int j    = ((blockIdx.x & 7) << 2) | ((blockIdx.x >> 3) & 3); // XCD-local slice
    const int b0   = bg * 32;
    const int tid  = threadIdx.x;
    const int lane = tid & 63;
    const int wave = tid >> 6;
    const s16x8 z8 = {0, 0, 0, 0, 0, 0, 0, 0};

    extern __shared__ __align__(16) char smem[];
    short* stg = (short*)smem;                         // SA/SB/SC
    float* hgl = (float*)(smem + LDS_STAGE * 2);       // [18][HSTR]
    float* sg0 = hgl + 18 * HSTR;                      // [32*48]
    float* sbb = sg0 + 32 * 48;                        // [3][4][16]

    // ---- wave role parameters (uniform per wave; loop-invariant)
    int abase, ak0, slot0;
    const short* wg0; const short* wg1; const short* wg2;
    {
        const short* wpk; int KT, kt0;
        switch (wave) {
            case 0:  wpk = packW0; KT = 16; kt0 = 0;  abase = LDS_SA; ak0 = 0; slot0 = 0;  break;
            case 1:  wpk = packW0; KT = 16; kt0 = 8;  abase = LDS_SA; ak0 = 8; slot0 = 1;  break;
            case 2:  wpk = packW1; KT = 32; kt0 = 0;  abase = LDS_SA; ak0 = 0; slot0 = 6;  break;
            case 3:  wpk = packW1; KT = 32; kt0 = 16; abase = LDS_SB; ak0 = 0; slot0 = 7;  break;
            case 4:  wpk = packW2; KT = 32; kt0 = 0;  abase = LDS_SB; ak0 = 0; slot0 = 12; break;
            default: wpk = packW2; KT = 32; kt0 = 16; abase = LDS_SC; ak0 = 0; slot0 = 13; break;
        }
        wg0 = wpk + ((size_t)((j * 3 + 0) * KT + kt0) * 512);
        wg1 = wpk + ((size_t)((j * 3 + 1) * KT + kt0) * 512);
        wg2 = wpk + ((size_t)((j * 3 + 2) * KT + kt0) * 512);
    }
    float* dr = hgl + (size_t)slot0 * HSTR;
    float* dz = hgl + (size_t)(slot0 + 2) * HSTR;
    float* dn = hgl + (size_t)(slot0 + 4) * HSTR;

    // ---- layer0 x-gate constants (g0 + b_hh0 folded for r,z)
    for (int c = tid; c < 32 * 48; c += 384) {
        int m = c / 48, col = c % 48;
        int g = col >> 4, ul = col & 15;
        int u = j * 16 + ul;
        float v = 0.f;
        if (u < H) {
            v = g0[(size_t)(b0 + m) * NP + g * H + u];
            if (g == 0) v += b_hh0[u];
            else if (g == 1) v += b_hh0[H + u];
        }
        sg0[m * 48 + col] = v;
    }
    if (tid < 48) {
        int l = tid >> 4, ul = tid & 15, u = j * 16 + ul;
        float br = 0.f, bz = 0.f, bxn = 0.f, bhn = 0.f;
        if (u < H) {
            if (l == 0) bhn = b_hh0[2 * H + u];
            else {
                const float* bi = (l == 1) ? b_ih1 : b_ih2;
                const float* bh = (l == 1) ? b_hh1 : b_hh2;
                br = bi[u] + bh[u]; bz = bi[H + u] + bh[H + u];
                bxn = bi[2 * H + u]; bhn = bh[2 * H + u];
            }
        }
        sbb[(l * 4 + 0) * 16 + ul] = br;  sbb[(l * 4 + 1) * 16 + ul] = bz;
        sbb[(l * 4 + 2) * 16 + ul] = bxn; sbb[(l * 4 + 3) * 16 + ul] = bhn;
    }
    __syncthreads();

    unsigned* mycnt = cnt + bg * 32;   // 128B-strided counters

    for (int s = 0; s < T_STEPS + 2; ++s) {
        const bool hasL0 = (s < T_STEPS);
        const bool hasL1 = (s >= 1 && s <= T_STEPS);
        const bool hasL2 = (s >= 2);
        const short* ysAm1 = ysA + (size_t)(s - 1) * BATCH * HP;
        const short* ysBm2 = ysB + (size_t)(s - 2) * BATCH * HP;
        const short* ysAm3 = ysA + (size_t)(s - 3) * BATCH * HP;

        // ================= PHASE A: coalesced staging of all three tiles ====
        #pragma unroll
        for (int i = 0; i < 6; i++) {
            int c = tid + i * 384;
            if (c < 2048) {
                int r = c >> 6, cc = c & 63;
                size_t goff = (size_t)(b0 + r) * HP + cc * 8;
                s16x8 va = z8, vb = z8, vc = z8;
                if (s >= 1 && s <= T_STEPS) va = *(const s16x8*)&ysAm1[goff];
                if (s >= 2)                 vb = *(const s16x8*)&ysBm2[goff];
                if (s >= 3) {
                    const ull* p = (const ull*)&ysAm3[goff];
                    union { ull q[2]; s16x8 v; } uu;
                    uu.q[0] = __hip_atomic_load(p,     __ATOMIC_RELAXED, __HIP_MEMORY_SCOPE_AGENT);
                    uu.q[1] = __hip_atomic_load(p + 1, __ATOMIC_RELAXED, __HIP_MEMORY_SCOPE_AGENT);
                    vc = uu.v;
                }
                int loff = r * SSTR + cc * 8;
                *(s16x8*)&stg[LDS_SA + loff] = va;
                *(s16x8*)&stg[LDS_SB + loff] = vb;
                *(s16x8*)&stg[LDS_SC + loff] = vc;
            }
        }
        __syncthreads();                                   // (1) tiles staged

        // ================= PHASE B: 6 roles, compile-time unrolled ==========
        {
            const bool active = (wave < 2) ? hasL0 : ((wave < 4) ? hasL1 : hasL2);
            if (active) {
                if (wave < 2) role_mfma<8>(stg, abase, ak0, wg0, wg1, wg2, dr, dz, dn, lane);
                else          role_mfma<16>(stg, abase, ak0, wg0, wg1, wg2, dr, dz, dn, lane);
            }
        }
        __syncthreads();                                   // (2) hgl complete

        // ================= PHASE C: all gates (768 items / 384 threads) =====
        #pragma unroll
        for (int it = 0; it < 2; it++) {
            int idx = tid + it * 384;
            int which = idx >> 8, id8 = idx & 255;
            int m = id8 >> 3, pr = id8 & 7;
            int b = b0 + m;
            if (which == 0 && hasL0) {
                short* dst = ysA + (size_t)s * BATCH * HP;
                unsigned pk = 0;
                #pragma unroll
                for (int e = 0; e < 2; e++) {
                    int ul = pr * 2 + e, u = j * 16 + ul, mo = m * 18 + ul;
                    float hv = 0.f;
                    if (u < H) {
                        float hr = hgl[0 * HSTR + mo] + hgl[1 * HSTR + mo];
                        float hz = hgl[2 * HSTR + mo] + hgl[3 * HSTR + mo];
                        float hn = hgl[4 * HSTR + mo] + hgl[5 * HSTR + mo];
                        float r = sigm(sg0[m * 48 + ul] + hr);
                        float z = sigm(sg0[m * 48 + 16 + ul] + hz);
                        float n = tanh_fast(sg0[m * 48 + 32 + ul] + r * (hn + sbb[3 * 16 + ul]));
                        float hold = bf2f(stg[LDS_SA + m * SSTR + u]);
                        hv = (1.f - z) * n + z * hold;
                    }
                    pk |= ((unsigned)(unsigned short)f2bf(hv)) << (16 * e);
                }
                __hip_atomic_store((unsigned*)&dst[(size_t)b * HP + j * 16 + pr * 2], pk,
                                   __ATOMIC_RELAXED, __HIP_MEMORY_SCOPE_AGENT);
            } else if (which == 1 && hasL1) {
                short* dst = ysB + (size_t)(s - 1) * BATCH * HP;
                unsigned pk = 0;
                #pragma unroll
                for (int e = 0; e < 2; e++) {
                    int ul = pr * 2 + e, u = j * 16 + ul, mo = m * 18 + ul;
                    float hv = 0.f;
                    if (u < H) {
                        float xr = hgl[6 * HSTR + mo]  + sbb[(4 + 0) * 16 + ul];
                        float hr = hgl[7 * HSTR + mo];
                        float xz = hgl[8 * HSTR + mo]  + sbb[(4 + 1) * 16 + ul];
                        float hz = hgl[9 * HSTR + mo];
                        float xn = hgl[10 * HSTR + mo] + sbb[(4 + 2) * 16 + ul];
                        float hn = hgl[11 * HSTR + mo] + sbb[(4 + 3) * 16 + ul];
                        float r = sigm(xr + hr);
                        float z = sigm(xz + hz);
                        float n = tanh_fast(xn + r * hn);
                        float hold = bf2f(stg[LDS_SB + m * SSTR + u]);
                        hv = (1.f - z) * n + z * hold;
                    }
                    pk |= ((unsigned)(unsigned short)f2bf(hv)) << (16 * e);
                }
                __hip_atomic_store((unsigned*)&dst[(size_t)b * HP + j * 16 + pr * 2], pk,
                                   __ATOMIC_RELAXED, __HIP_MEMORY_SCOPE_AGENT);
            } else if (which == 2 && hasL2) {
                short* dst = ysA + (size_t)(s - 2) * BATCH * HP;
                unsigned pk = 0;
                #pragma unroll
                for (int e = 0; e < 2; e++) {
                    int ul = pr * 2 + e, u = j * 16 + ul, mo = m * 18 + ul;
                    float hv = 0.f;
                    if (u < H) {
                        float xr = hgl[12 * HSTR + mo] + sbb[(8 + 0) * 16 + ul];
                        float hr = hgl[13 * HSTR + mo];
                        float xz = hgl[14 * HSTR + mo] + sbb[(8 + 1) * 16 + ul];
                        float hz = hgl[15 * HSTR + mo];
                        float xn = hgl[16 * HSTR + mo] + sbb[(8 + 2) * 16 + ul];
                        float hn = hgl[17 * HSTR + mo] + sbb[(8 + 3) * 16 + ul];
                        float r = sigm(xr + hr);
                        float z = sigm(xz + hz);
                        float n = tanh_fast(xn + r * hn);
                        float hold = bf2f(stg[LDS_SC + m * SSTR + u]);
                        hv = (1.f - z) * n + z * hold;
                    }
                    pk |= ((unsigned)(unsigned short)f2bf(hv)) << (16 * e);
                }
                __hip_atomic_store((unsigned*)&dst[(size_t)b * HP + j * 16 + pr * 2], pk,
                                   __ATOMIC_RELAXED, __HIP_MEMORY_SCOPE_AGENT);
            }
        }
        __syncthreads();    // (3) every wave's sc1 stores drained at barrier

        // ---- per-bg 32-block barrier: relaxed add + relaxed poll
        if (tid == 0) {
            asm volatile("s_waitcnt vmcnt(0)" ::: "memory");
            __hip_atomic_fetch_add(mycnt, 1u, __ATOMIC_RELAXED, __HIP_MEMORY_SCOPE_AGENT);
            unsigned tgt = 32u * (unsigned)(s + 1);
            while (__hip_atomic_load(mycnt, __ATOMIC_RELAXED, __HIP_MEMORY_SCOPE_AGENT) < tgt) {}
        }
        __syncthreads();                                   // (4)
    }
}

// ---------------------------------------------------------------------------
// fc2 + transpose (reads ysA = layer2 output; fresh kernel => coherent)
// ---------------------------------------------------------------------------
__global__ __launch_bounds__(256, 1)
void k_fc2(const short* __restrict__ ys2, const short* __restrict__ fc2p,
           const float* __restrict__ fc2_b, float* __restrict__ out) {
    int b = blockIdx.x;
    int tid = threadIdx.x, lane = tid & 63, wave = tid >> 6;
    const s16x8 zf = {0, 0, 0, 0, 0, 0, 0, 0};
    for (int ntile = wave; ntile < 18; ntile += 4) {
        int tt = ntile * 16 + (lane & 15);
        s16x8 bf[16];
        for (int kt = 0; kt < 16; kt++) {
            if (tt < T_STEPS)
                bf[kt] = *(const s16x8*)&ys2[((size_t)tt * BATCH + b) * HP + kt * 32 + (lane >> 4) * 8];
            else
                bf[kt] = zf;
        }
        for (int mt = 0; mt < 5; mt++) {
            f32x4 acc = {0.f, 0.f, 0.f, 0.f};
            for (int kt = 0; kt < 16; kt++) {
                s16x8 af = *(const s16x8*)&fc2p[(((size_t)mt * 16 + kt) * 64 + lane) * 8];
                acc = __builtin_amdgcn_mfma_f32_16x16x32_bf16(af, bf[kt], acc, 0, 0, 0);
            }
            int obase = mt * 16 + (lane >> 4) * 4;
            for (int r = 0; r < 4; r++) {
                int o = obase + r;
                if (o < O_OUT && tt < T_STEPS)
                    out[((size_t)b * O_OUT + o) * T_STEPS + tt] = acc[r] + fc2_b[o];
            }
        }
    }
}

// ---------------------------------------------------------------------------
extern "C" void kernel_launch(void* const* d_in, const int* in_sizes, int n_in,
                              void* d_out, int out_size, void* d_ws, size_t ws_size,
                              hipStream_t stream) {
    const float* x     = (const float*)d_in[0];
    const float* fc1_w = (const float*)d_in[1];
    const float* fc1_b = (const float*)d_in[2];
    const float* w_ih0 = (const float*)d_in[3];
    const float* w_hh0 = (const float*)d_in[4];
    const float* b_ih0 = (const float*)d_in[5];
    const float* b_hh0 = (const float*)d_in[6];
    const float* w_ih1 = (const float*)d_in[7];
    const float* w_hh1 = (const float*)d_in[8];
    const float* b_ih1 = (const float*)d_in[9];
    const float* b_hh1 = (const float*)d_in[10];
    const float* w_ih2 = (const float*)d_in[11];
    const float* w_hh2 = (const float*)d_in[12];
    const float* b_ih2 = (const float*)d_in[13];
    const float* b_hh2 = (const float*)d_in[14];
    const float* fc2_w = (const float*)d_in[15];
    const float* fc2_b = (const float*)d_in[16];
    float* out = (float*)d_out;

    char* p = (char*)d_ws;
    auto alloc = [&](size_t bytes) {
        char* r = p; p += (bytes + 255) & ~(size_t)255; return r;
    };
    short* packW0 = (short*)alloc((size_t)32 * 3 * 16 * 64 * 8 * 2);
    short* packW1 = (short*)alloc((size_t)32 * 3 * 32 * 64 * 8 * 2);
    short* packW2 = (short*)alloc((size_t)32 * 3 * 32 * 64 * 8 * 2);
    short* packF  = (short*)alloc((size_t)80 * 64 * 8 * 2);
    float* hin    = (float*)alloc((size_t)BATCH * 64 * 4);
    float* g0     = (float*)alloc((size_t)BATCH * NP * 4);
    unsigned* cnt = (unsigned*)alloc(256 * 4);
    short* ysA    = (short*)alloc((size_t)T_STEPS * BATCH * HP * 2);
    short* ysB    = (short*)alloc((size_t)T_STEPS * BATCH * HP * 2);

    // opt in to >64KB dynamic LDS (host-side attribute; graph-capture safe)
    static bool attr_set = false;
    if (!attr_set) {
        (void)hipFuncSetAttribute((const void*)k_gru_persist,
                                  hipFuncAttributeMaxDynamicSharedMemorySize,
                                  DYN_LDS);
        attr_set = true;
    }

    hipMemsetAsync(cnt, 0, 256 * 4, stream);
    k_pack_gru<<<32 * 3 * 16, 64, 0, stream>>>(nullptr, w_hh0, packW0, 16);
    k_pack_gru<<<32 * 3 * 32, 64, 0, stream>>>(w_ih1, w_hh1, packW1, 32);
    k_pack_gru<<<32 * 3 * 32, 64, 0, stream>>>(w_ih2, w_hh2, packW2, 32);
    k_pack_fc2<<<80, 64, 0, stream>>>(fc2_w, packF);
    k_hin<<<BATCH, 64, 0, stream>>>(x, fc1_w, fc1_b, hin);
    k_g0<<<BATCH, 256, 0, stream>>>(hin, w_ih0, b_ih0, g0);

    k_gru_persist<<<256, 384, DYN_LDS, stream>>>(packW0, packW1, packW2, g0,
                                                 b_hh0, b_ih1, b_hh1, b_ih2, b_hh2,
                                                 ysA, ysB, cnt);

    k_fc2<<<BATCH, 256, 0, stream>>>(ysA, packF, fc2_b, out);
}